// Round 1
// baseline (15352.196 us; speedup 1.0000x reference)
//
#include <hip/hip_runtime.h>
#include <hip/hip_bf16.h>

// Temporal_Attention_Net: LSTM(ragged, B=256,T<=383,D=H=512) -> fc1 -> fc2 ->
// concrete-relaxation attention -> per-person segment sum -> 2-layer MLP.
// Round 1: correctness-first fp32 baseline. bf16 only for bulk ws tensors
// (xW gate preactivations, flat lstm output) to cut workspace to ~340 MB.

typedef __hip_bfloat16 bf16;

#define B_PERSONS 256
#define D_IN 512
#define H_SZ 512
#define G4 2048          // 4*H
#define T_MAX 383        // max(LENGTHS) = 128 + 255, fixed by the reference
#define BIAS_C 0.0001f

__device__ __forceinline__ float sigmoidf_(float x){ return 1.0f/(1.0f + __expf(-x)); }

// ---------------- setup: offsets prefix-sum, bias sum, zero h/c ----------------
__global__ void setup_k(const int* __restrict__ len,
                        const float* __restrict__ b_ih, const float* __restrict__ b_hh,
                        int* __restrict__ offsets, float* __restrict__ bsum,
                        float* __restrict__ hA, float* __restrict__ hB,
                        float* __restrict__ cst)
{
  int tid = threadIdx.x, bid = blockIdx.x;
  int gt = bid * 256 + tid;
  int tot = B_PERSONS * H_SZ;
  int nth = gridDim.x * 256;
  for (int i = gt; i < tot; i += nth){ hA[i] = 0.f; hB[i] = 0.f; cst[i] = 0.f; }
  if (bid == 0){
    for (int g = tid; g < G4; g += 256) bsum[g] = b_ih[g] + b_hh[g];
    if (tid == 0){
      int acc = 0;
      for (int p = 0; p < B_PERSONS; ++p){ offsets[p] = acc; acc += len[p]; }
      offsets[B_PERSONS] = acc;
    }
  }
}

// ---------------- generic NT GEMM: C[M,ncols] = A[M,512] * Bw[ncols,512]^T + bias ---
// A and Bw are K-contiguous (row-major, K=512 inner). 64x64 tile, 256 thr, 4x4 micro.
template<typename AT, typename OT>
__global__ __launch_bounds__(256) void gemm_nt(
    const AT* __restrict__ A, const float* __restrict__ Bw,
    const float* __restrict__ bias, OT* __restrict__ C,
    int M, int ncols)
{
  __shared__ float As[64][33];
  __shared__ float Bs[64][33];
  int tid = threadIdx.x;
  int m0 = blockIdx.y * 64;
  int n0 = blockIdx.x * 64;
  int tx = tid & 15, ty = tid >> 4;
  float acc[4][4] = {};
  for (int kc = 0; kc < 512; kc += 32){
    __syncthreads();
#pragma unroll
    for (int i = 0; i < 8; ++i){
      int e = tid + i * 256;            // 0..2047
      int r = e >> 5, kk = e & 31;
      int mr = m0 + r;
      As[r][kk] = (mr < M) ? (float)A[(size_t)mr * 512 + kc + kk] : 0.f;
      Bs[r][kk] = Bw[(size_t)(n0 + r) * 512 + kc + kk];
    }
    __syncthreads();
#pragma unroll
    for (int kk = 0; kk < 32; ++kk){
      float a[4], b[4];
#pragma unroll
      for (int i = 0; i < 4; ++i){ a[i] = As[ty*4+i][kk]; b[i] = Bs[tx*4+i][kk]; }
#pragma unroll
      for (int i = 0; i < 4; ++i)
#pragma unroll
        for (int j = 0; j < 4; ++j) acc[i][j] += a[i]*b[j];
    }
  }
#pragma unroll
  for (int i = 0; i < 4; ++i){
    int m = m0 + ty*4 + i;
    if (m >= M) continue;
#pragma unroll
    for (int j = 0; j < 4; ++j){
      int n = n0 + tx*4 + j;
      float v = acc[i][j] + bias[n];
      C[(size_t)m * ncols + n] = (OT)v;
    }
  }
}

// ---------------- one LSTM time step: gates = xW[row] + h @ W_hh^T; cell update ----
// Tile: 16 persons x 32 j-cols, computing all 4 gates per (p,j). Grid 16x16=256.
#define PERS 16
#define JT 32
__global__ __launch_bounds__(256) void lstm_step(
    const float* __restrict__ hin, float* __restrict__ hout,
    float* __restrict__ cst, const bf16* __restrict__ xW,
    const float* __restrict__ Whh, bf16* __restrict__ flat,
    const int* __restrict__ offsets, const int* __restrict__ len, int t)
{
  __shared__ float hs[PERS][516];        // +4 pad: banks spread for strided reads
  __shared__ float wsh[4*JT][33];
  __shared__ int anyact;
  int tid = threadIdx.x;
  int j0 = blockIdx.x * JT;
  int p0 = blockIdx.y * PERS;
  if (tid == 0) anyact = 0;
  __syncthreads();
  if (tid < PERS && t < len[p0 + tid]) anyact = 1;
  __syncthreads();
  if (!anyact) return;                   // whole person-tile finished -> skip

  // stage h tile (16x512 fp32) into LDS
#pragma unroll
  for (int i = 0; i < 8; ++i){
    int f4 = tid + i * 256;              // 0..2047 float4 slots
    int p = f4 >> 7, k4 = (f4 & 127) << 2;
    float4 v = *(const float4*)&hin[(size_t)(p0 + p) * 512 + k4];
    *(float4*)&hs[p][k4] = v;
  }
  int jl = tid & 31;                     // j lane (0..31)
  int pl = tid >> 5;                     // person sub (0..7), handles pl and pl+8
  float acc[2][4] = {};
  for (int kc = 0; kc < 512; kc += 32){
    __syncthreads();
#pragma unroll
    for (int i = 0; i < 16; ++i){
      int e = tid + i * 256;             // 0..4095
      int r = e >> 5, kk = e & 31;       // r = gate*32 + j
      int gate = r >> 5, j = r & 31;
      wsh[r][kk] = Whh[(size_t)(gate * 512 + j0 + j) * 512 + kc + kk];
    }
    __syncthreads();
#pragma unroll
    for (int kk = 0; kk < 32; ++kk){
      float h1 = hs[pl][kc + kk];
      float h2 = hs[pl + 8][kc + kk];
      float wi = wsh[      jl][kk];
      float wf = wsh[ 32 + jl][kk];
      float wg = wsh[ 64 + jl][kk];
      float wo = wsh[ 96 + jl][kk];
      acc[0][0] += h1*wi; acc[0][1] += h1*wf; acc[0][2] += h1*wg; acc[0][3] += h1*wo;
      acc[1][0] += h2*wi; acc[1][1] += h2*wf; acc[1][2] += h2*wg; acc[1][3] += h2*wo;
    }
  }
#pragma unroll
  for (int rep = 0; rep < 2; ++rep){
    int p = p0 + pl + rep * 8;
    if (t >= len[p]) continue;           // person already finished
    int row = offsets[p] + t;
    int j = j0 + jl;
    size_t xb = (size_t)row * G4;
    float pi = acc[rep][0] + (float)xW[xb +        j];
    float pf = acc[rep][1] + (float)xW[xb +  512 + j];
    float pg = acc[rep][2] + (float)xW[xb + 1024 + j];
    float po = acc[rep][3] + (float)xW[xb + 1536 + j];
    int ci = p * 512 + j;
    float cc = cst[ci];
    float ig = sigmoidf_(pi);
    float fg = sigmoidf_(pf);
    float gg = tanhf(pg);
    float og = sigmoidf_(po);
    float cn = fg * cc + ig * gg;
    float hn = og * tanhf(cn);
    cst[ci] = cn;
    hout[(size_t)p * 512 + j] = hn;
    flat[(size_t)row * 512 + j] = (bf16)hn;
  }
}

// ---------------- fc2 + sampling + att-weighted segment sum (one block / person) ---
__global__ __launch_bounds__(256) void att_seg_k(
    const float* __restrict__ pz,        // passed_Z in d_out, [N,512] fp32
    const bf16* __restrict__ flat,
    const float* __restrict__ eps_u,
    const float* __restrict__ fc2W, const float* __restrict__ fc2b,
    const int* __restrict__ offsets, const int* __restrict__ len,
    float* __restrict__ seg)
{
  __shared__ float red[4];
  __shared__ float satt;
  int p = blockIdx.x, tid = threadIdx.x;
  int n0 = offsets[p], L = len[p];
  float w1 = fc2W[tid], w2 = fc2W[tid + 256];
  float a0 = 0.f, a1 = 0.f;
  for (int tt = 0; tt < L; ++tt){
    size_t rb = (size_t)(n0 + tt) * 512;
    float part = pz[rb + tid] * w1 + pz[rb + 256 + tid] * w2;
#pragma unroll
    for (int off = 32; off > 0; off >>= 1) part += __shfl_down(part, off);
    if ((tid & 63) == 0) red[tid >> 6] = part;
    __syncthreads();
    if (tid == 0){
      float logit = red[0] + red[1] + red[2] + red[3] + fc2b[0];
      float u = eps_u[n0 + tt];
      float eps = (2.f * BIAS_C - 1.f) * u + (1.f - BIAS_C);
      float gate = __logf(eps) - __logf(1.f - eps) + logit;
      satt = sigmoidf_(gate);
    }
    __syncthreads();
    float att = satt;
    a0 += (float)flat[rb + tid] * att;
    a1 += (float)flat[rb + 256 + tid] * att;
  }
  seg[(size_t)p * 512 + tid] = a0;
  seg[(size_t)p * 512 + 256 + tid] = a1;
}

// ---------------- final 2-layer MLP (one wave / person) ----------------
__global__ void final_k(const float* __restrict__ seg,
    const float* __restrict__ m1W, const float* __restrict__ m1b,
    const float* __restrict__ m2W, const float* __restrict__ m2b,
    float* __restrict__ outF)
{
  __shared__ float sv[512];
  __shared__ float m1s[16];
  int p = blockIdx.x, tid = threadIdx.x;   // 64 threads
  for (int i = tid; i < 512; i += 64) sv[i] = seg[p * 512 + i];
  __syncthreads();
  if (tid < 16){
    float a = m1b[tid];
    for (int k = 0; k < 512; ++k) a += sv[k] * m1W[tid * 512 + k];
    m1s[tid] = a;
  }
  __syncthreads();
  if (tid < 2){
    float a = m2b[tid];
    for (int o = 0; o < 16; ++o) a += m1s[o] * m2W[tid * 16 + o];
    outF[p * 2 + tid] = a;
  }
}

extern "C" void kernel_launch(void* const* d_in, const int* in_sizes, int n_in,
                              void* d_out, int out_size, void* d_ws, size_t ws_size,
                              hipStream_t stream)
{
  const float* lstm_input = (const float*)d_in[0];
  const float* eps_u  = (const float*)d_in[1];
  const float* W_ih   = (const float*)d_in[2];
  const float* W_hh   = (const float*)d_in[3];
  const float* b_ih   = (const float*)d_in[4];
  const float* b_hh   = (const float*)d_in[5];
  const float* fc1_W  = (const float*)d_in[6];
  const float* fc1_b  = (const float*)d_in[7];
  const float* fc2_W  = (const float*)d_in[8];
  const float* fc2_b  = (const float*)d_in[9];
  const float* m1W    = (const float*)d_in[10];
  const float* m1b    = (const float*)d_in[11];
  const float* m2W    = (const float*)d_in[12];
  const float* m2b    = (const float*)d_in[13];
  const int*   lengths= (const int*)d_in[14];

  int N = in_sizes[0] / D_IN;            // 65408

  float* outFinal = (float*)d_out;       // [B,2]
  float* passedZ  = (float*)d_out + 512; // [N,512]

  // workspace carve-up (~340 MB)
  char* w = (char*)d_ws;
  int*   offsets = (int*)w;                        // 257 ints
  float* bsum    = (float*)(w + 4096);             // 2048 fp32
  float* hA      = (float*)(w + 16384);            // [B,512] fp32
  float* hB      = hA + B_PERSONS * H_SZ;
  float* cst     = hB + B_PERSONS * H_SZ;
  float* seg     = cst + B_PERSONS * H_SZ;
  bf16*  flat    = (bf16*)(seg + B_PERSONS * H_SZ);    // [N,512] bf16
  bf16*  xW      = flat + (size_t)N * H_SZ;            // [N,2048] bf16
  (void)ws_size; (void)n_in; (void)out_size;

  setup_k<<<64, 256, 0, stream>>>(lengths, b_ih, b_hh, offsets, bsum, hA, hB, cst);

  // xW = lstm_input @ W_ih^T + (b_ih + b_hh)  -> bf16 ws
  dim3 g2(G4 / 64, (N + 63) / 64);
  gemm_nt<float, bf16><<<g2, 256, 0, stream>>>(lstm_input, W_ih, bsum, xW, N, G4);

  // sequential recurrence, ping-pong h buffers
  dim3 gs(H_SZ / JT, B_PERSONS / PERS);
  for (int t = 0; t < T_MAX; ++t){
    const float* hi = (t & 1) ? hB : hA;
    float*       ho = (t & 1) ? hA : hB;
    lstm_step<<<gs, 256, 0, stream>>>(hi, ho, cst, xW, W_hh, flat, offsets, lengths, t);
  }

  // passed_Z = flat @ fc1_W^T + fc1_b  -> d_out
  dim3 g4(H_SZ / 64, (N + 63) / 64);
  gemm_nt<bf16, float><<<g4, 256, 0, stream>>>(flat, fc1_W, fc1_b, passedZ, N, H_SZ);

  att_seg_k<<<B_PERSONS, 256, 0, stream>>>(passedZ, flat, eps_u, fc2_W, fc2_b,
                                           offsets, lengths, seg);
  final_k<<<B_PERSONS, 64, 0, stream>>>(seg, m1W, m1b, m2W, m2b, outFinal);
}

// Round 4
// 4224.846 us; speedup vs baseline: 3.6338x; 3.6338x over previous
//
#include <hip/hip_runtime.h>
#include <hip/hip_bf16.h>

// Temporal_Attention_Net — Round 2 kernel (2nd resubmit; broker timeouts, never ran).
//  - xW = x @ W_ih^T + (b_ih+b_hh): 128x128-tile MFMA GEMM (fp32 A converted in staging)
//  - recurrence: per-step MFMA kernel, 64 persons x (4 gates x 16 j) per block,
//    full-K W_hh tile in LDS (XOR-swizzled via pre-swizzled global source),
//    h loaded global->VGPR direct, xW slice prefetched to LDS, fused cell update.
//  - fc1: bf16 MFMA GEMM (global_load_lds path) -> fp32 passed_Z in d_out
//  - att logits + sampling: parallel per-row; seg-sum: one block/person.

typedef unsigned short ushort_t;
typedef __attribute__((ext_vector_type(8))) short bf16x8;
typedef __attribute__((ext_vector_type(4))) float f32x4;

#define NPERS 256
#define K512 512
#define G4 2048
#define T_MAX 383
#define BIAS_C 0.0001f

__device__ __forceinline__ unsigned f2bf_u(float f){
  unsigned u = __float_as_uint(f);
  return (u + 0x7FFFu + ((u >> 16) & 1u)) >> 16;   // RTNE
}
__device__ __forceinline__ float bf2f(unsigned short u){
  return __uint_as_float(((unsigned)u) << 16);
}
__device__ __forceinline__ float sigm(float x){ return 1.f/(1.f + __expf(-x)); }
__device__ __forceinline__ float tanh_f(float x){
  x = fminf(fmaxf(x, -15.f), 15.f);
  float e = __expf(2.f*x);
  return (e - 1.f)/(e + 1.f);
}
__device__ __forceinline__ void gl_lds16(const void* g, void* l){
  __builtin_amdgcn_global_load_lds(
      (const __attribute__((address_space(1))) unsigned*)g,
      (__attribute__((address_space(3))) unsigned*)l, 16, 0, 0);
}

// ---------------- setup: offsets prefix-sum, bias sum, zero cst/hA/hB ----------------
__global__ void setup_k(const int* __restrict__ len,
                        const float* __restrict__ b_ih, const float* __restrict__ b_hh,
                        int* __restrict__ offsets, float* __restrict__ bsum,
                        uint4* __restrict__ zero_base)
{
  int tid = threadIdx.x, bid = blockIdx.x;
  int gt = bid * 256 + tid;
  for (int i = gt; i < 65536; i += 64 * 256) zero_base[i] = make_uint4(0,0,0,0);
  if (bid == 0){
    for (int g = tid; g < G4; g += 256) bsum[g] = b_ih[g] + b_hh[g];
    if (tid == 0){
      int acc = 0;
      for (int p = 0; p < NPERS; ++p){ offsets[p] = acc; acc += len[p]; }
      offsets[NPERS] = acc;
    }
  }
}

// ---------------- fp32 -> bf16 bulk convert (8 elems / thread) ----------------
__global__ void conv_k(const float* __restrict__ src, ushort_t* __restrict__ dst, int n8)
{
  int i = blockIdx.x * 256 + threadIdx.x;
  if (i >= n8) return;
  const float4* s = (const float4*)src + (size_t)i * 2;
  float4 a = s[0], b = s[1];
  uint4 pk;
  pk.x = f2bf_u(a.x) | (f2bf_u(a.y) << 16);
  pk.y = f2bf_u(a.z) | (f2bf_u(a.w) << 16);
  pk.z = f2bf_u(b.x) | (f2bf_u(b.y) << 16);
  pk.w = f2bf_u(b.z) | (f2bf_u(b.w) << 16);
  *(uint4*)(dst + (size_t)i * 8) = pk;
}

// ---------------- MFMA NT GEMM: C[M,ldc-slice] = A[M,512] * Bw[ncols,512]^T + bias ----
// 128x128 tile, 4 waves (2x2 of 64x64), BK=32, single-buffered LDS.
template<bool A_IS_F32, bool OUT_BF16>
__global__ __launch_bounds__(256, 2) void mfma_gemm_nt(
    const void* __restrict__ Av, const ushort_t* __restrict__ Bw,
    const float* __restrict__ bias, void* __restrict__ Cv, int M, int ldc)
{
  __shared__ __align__(16) short As[128 * 32];
  __shared__ __align__(16) short Bs[128 * 32];
  int tid = threadIdx.x;
  int l = tid & 63, w = tid >> 6;
  int wr = w >> 1, wc = w & 1;
  int m0 = blockIdx.y * 128, n0 = blockIdx.x * 128;
  f32x4 acc[4][4] = {};
  for (int kc = 0; kc < K512; kc += 32){
#pragma unroll
    for (int i = 0; i < 2; ++i){              // B tile: 128 rows x 32 k, bf16
      int e = i * 256 + tid; int r = e >> 2, c8 = (e & 3) * 8;
      gl_lds16(Bw + (size_t)(n0 + r) * K512 + kc + c8, (char*)Bs + e * 16);
    }
    if constexpr (A_IS_F32){
      const float* Af = (const float*)Av;
#pragma unroll
      for (int i = 0; i < 2; ++i){
        int e = i * 256 + tid; int r = e >> 2, c8 = (e & 3) * 8;
        int mr = m0 + r; if (mr >= M) mr = M - 1;
        const float4* s = (const float4*)(Af + (size_t)mr * K512 + kc + c8);
        float4 x = s[0], y = s[1];
        uint4 pk;
        pk.x = f2bf_u(x.x) | (f2bf_u(x.y) << 16);
        pk.y = f2bf_u(x.z) | (f2bf_u(x.w) << 16);
        pk.z = f2bf_u(y.x) | (f2bf_u(y.y) << 16);
        pk.w = f2bf_u(y.z) | (f2bf_u(y.w) << 16);
        *(uint4*)((char*)As + e * 16) = pk;
      }
    } else {
      const ushort_t* Ab = (const ushort_t*)Av;
#pragma unroll
      for (int i = 0; i < 2; ++i){
        int e = i * 256 + tid; int r = e >> 2, c8 = (e & 3) * 8;
        int mr = m0 + r; if (mr >= M) mr = M - 1;
        gl_lds16(Ab + (size_t)mr * K512 + kc + c8, (char*)As + e * 16);
      }
    }
    __syncthreads();
    bf16x8 af[4], bfr[4];
#pragma unroll
    for (int i = 0; i < 4; ++i){
      af[i]  = *(const bf16x8*)&As[(wr * 64 + i * 16 + (l & 15)) * 32 + (l >> 4) * 8];
      bfr[i] = *(const bf16x8*)&Bs[(wc * 64 + i * 16 + (l & 15)) * 32 + (l >> 4) * 8];
    }
#pragma unroll
    for (int mi = 0; mi < 4; ++mi)
#pragma unroll
      for (int ni = 0; ni < 4; ++ni)
        acc[mi][ni] = __builtin_amdgcn_mfma_f32_16x16x32_bf16(af[mi], bfr[ni], acc[mi][ni], 0, 0, 0);
    __syncthreads();
  }
#pragma unroll
  for (int mi = 0; mi < 4; ++mi){
    int row0 = m0 + wr * 64 + mi * 16 + (l >> 4) * 4;
#pragma unroll
    for (int ni = 0; ni < 4; ++ni){
      int col = n0 + wc * 64 + ni * 16 + (l & 15);
      float bv = bias[col];
      f32x4 v = acc[mi][ni];
#pragma unroll
      for (int r = 0; r < 4; ++r){
        int row = row0 + r;
        if (row < M){
          float val = v[r] + bv;
          if constexpr (OUT_BF16) ((ushort_t*)Cv)[(size_t)row * ldc + col] = (ushort_t)f2bf_u(val);
          else                    ((float*)Cv)[(size_t)row * ldc + col] = val;
        }
      }
    }
  }
}

// ---------------- one LSTM step: 64 persons x (4 gates x 16 j) per block -------------
// B (W_hh gather tile, 64 rows x 512 k) staged full-K in LDS with XOR-swizzled source;
// A (h) fragments loaded global->VGPR; xW epilogue slice prefetched to LDS.
__global__ __launch_bounds__(256) void step_k(
    const ushort_t* __restrict__ hin, ushort_t* __restrict__ hout,
    float* __restrict__ cst, const ushort_t* __restrict__ xW,
    const ushort_t* __restrict__ Whh, ushort_t* __restrict__ flat,
    const int* __restrict__ offsets, const int* __restrict__ len, int t)
{
  __shared__ __align__(16) short wsm[64 * 512];   // 64 KB: [gate*16+jj][k] swizzled
  __shared__ __align__(16) short xs[64 * 64];     // 8 KB:  [person][gate*16+jj]
  __shared__ int anyact;
  int tid = threadIdx.x;
  int j0 = blockIdx.x * 16;
  int p0 = blockIdx.y * 64;
  if (tid == 0) anyact = 0;
  __syncthreads();
  if (tid < 64 && t < len[p0 + tid]) anyact = 1;
  __syncthreads();
  if (!anyact) return;
  int l = tid & 63, w = tid >> 6;

  // stage W_hh gather tile, full K. slot e -> (row r=e>>6, chunk cl=e&63); the chunk
  // that must land here is cl ^ (r&7) (involution), so swizzled reads are ~conflict-free.
#pragma unroll
  for (int i = 0; i < 16; ++i){
    int e = i * 256 + tid; int r = e >> 6, cl = e & 63;
    int cs = cl ^ (r & 7);
    int brow = (r >> 4) * K512 + j0 + (r & 15);
    gl_lds16(Whh + (size_t)brow * K512 + cs * 8, (char*)wsm + e * 16);
  }
  // stage xW slice: xs[p][gate*16 + h*8 ..] ; rows for finished persons are
  // in-bounds garbage (discarded in epilogue).
#pragma unroll
  for (int i = 0; i < 2; ++i){
    int e = i * 256 + tid; int p = e >> 3, sub = e & 7;
    int gate = sub >> 1, h8 = (sub & 1) * 8;
    int row = offsets[p0 + p] + t;
    gl_lds16(xW + (size_t)row * G4 + gate * K512 + j0 + h8, (char*)xs + e * 16);
  }
  __syncthreads();

  const ushort_t* arow_p = hin + (size_t)(p0 + w * 16 + (l & 15)) * K512 + (l >> 4) * 8;
  f32x4 acc[4] = {};
#pragma unroll
  for (int kc = 0; kc < K512; kc += 32){
    bf16x8 a = *(const bf16x8*)(arow_p + kc);
    int ck = (kc >> 3) + (l >> 4);
#pragma unroll
    for (int g = 0; g < 4; ++g){
      int br = g * 16 + (l & 15);
      bf16x8 b = *(const bf16x8*)&wsm[br * K512 + (ck ^ (br & 7)) * 8];
      acc[g] = __builtin_amdgcn_mfma_f32_16x16x32_bf16(a, b, acc[g], 0, 0, 0);
    }
  }

  int jj = l & 15, j = j0 + jj;
  int plb = w * 16 + (l >> 4) * 4;
#pragma unroll
  for (int q = 0; q < 4; ++q){
    int pl_ = plb + q, p = p0 + pl_;
    if (t >= len[p]) continue;
    int row = offsets[p] + t;
    float pi = acc[0][q] + bf2f(((const ushort_t*)xs)[pl_ * 64 + jj]);
    float pf = acc[1][q] + bf2f(((const ushort_t*)xs)[pl_ * 64 + 16 + jj]);
    float pg = acc[2][q] + bf2f(((const ushort_t*)xs)[pl_ * 64 + 32 + jj]);
    float po = acc[3][q] + bf2f(((const ushort_t*)xs)[pl_ * 64 + 48 + jj]);
    int ci = p * K512 + j;
    float cc = cst[ci];
    float cn = sigm(pf) * cc + sigm(pi) * tanh_f(pg);
    float hn = sigm(po) * tanh_f(cn);
    cst[ci] = cn;
    ushort_t hb = (ushort_t)f2bf_u(hn);
    hout[ci] = hb;
    flat[(size_t)row * K512 + j] = hb;
  }
}

// ---------------- att logits + sampling: one wave per row ----------------
__global__ __launch_bounds__(256) void att_k(
    const float* __restrict__ pz, const float* __restrict__ eps_u,
    const float* __restrict__ fc2W, const float* __restrict__ fc2b,
    float* __restrict__ att, int N)
{
  int w = threadIdx.x >> 6, l = threadIdx.x & 63;
  int n = blockIdx.x * 4 + w;
  if (n >= N) return;
  const float4* rp = (const float4*)(pz + (size_t)n * K512);
  const float4* wp = (const float4*)fc2W;
  float4 a0 = rp[l * 2], a1 = rp[l * 2 + 1];
  float4 w0 = wp[l * 2], w1 = wp[l * 2 + 1];
  float s = a0.x*w0.x + a0.y*w0.y + a0.z*w0.z + a0.w*w0.w
          + a1.x*w1.x + a1.y*w1.y + a1.z*w1.z + a1.w*w1.w;
#pragma unroll
  for (int off = 32; off; off >>= 1) s += __shfl_down(s, off);
  if (l == 0){
    float logit = s + fc2b[0];
    float u = eps_u[n];
    float eps = (2.f * BIAS_C - 1.f) * u + (1.f - BIAS_C);
    float gate = __logf(eps) - __logf(1.f - eps) + logit;
    att[n] = sigm(gate);
  }
}

// ---------------- att-weighted per-person sum ----------------
__global__ __launch_bounds__(256) void seg_k(
    const ushort_t* __restrict__ flat, const float* __restrict__ att,
    const int* __restrict__ offsets, const int* __restrict__ len,
    float* __restrict__ seg)
{
  int p = blockIdx.x, tid = threadIdx.x;
  int n0 = offsets[p], L = len[p];
  float a0 = 0.f, a1 = 0.f;
  for (int tt = 0; tt < L; ++tt){
    float av = att[n0 + tt];
    size_t rb = (size_t)(n0 + tt) * K512;
    a0 += bf2f(flat[rb + tid]) * av;
    a1 += bf2f(flat[rb + 256 + tid]) * av;
  }
  seg[p * K512 + tid] = a0;
  seg[p * K512 + 256 + tid] = a1;
}

// ---------------- final 2-layer MLP ----------------
__global__ void final_k(const float* __restrict__ seg,
    const float* __restrict__ m1W, const float* __restrict__ m1b,
    const float* __restrict__ m2W, const float* __restrict__ m2b,
    float* __restrict__ outF)
{
  __shared__ float sv[512];
  __shared__ float m1s[16];
  int p = blockIdx.x, tid = threadIdx.x;   // 64 threads
  for (int i = tid; i < 512; i += 64) sv[i] = seg[p * 512 + i];
  __syncthreads();
  if (tid < 16){
    float a = m1b[tid];
    for (int k = 0; k < 512; ++k) a += sv[k] * m1W[tid * 512 + k];
    m1s[tid] = a;
  }
  __syncthreads();
  if (tid < 2){
    float a = m2b[tid];
    for (int o = 0; o < 16; ++o) a += m1s[o] * m2W[tid * 16 + o];
    outF[p * 2 + tid] = a;
  }
}

extern "C" void kernel_launch(void* const* d_in, const int* in_sizes, int n_in,
                              void* d_out, int out_size, void* d_ws, size_t ws_size,
                              hipStream_t stream)
{
  const float* lstm_input = (const float*)d_in[0];
  const float* eps_u  = (const float*)d_in[1];
  const float* W_ih   = (const float*)d_in[2];
  const float* W_hh   = (const float*)d_in[3];
  const float* b_ih   = (const float*)d_in[4];
  const float* b_hh   = (const float*)d_in[5];
  const float* fc1_W  = (const float*)d_in[6];
  const float* fc1_b  = (const float*)d_in[7];
  const float* fc2_W  = (const float*)d_in[8];
  const float* fc2_b  = (const float*)d_in[9];
  const float* m1W    = (const float*)d_in[10];
  const float* m1b    = (const float*)d_in[11];
  const float* m2W    = (const float*)d_in[12];
  const float* m2b    = (const float*)d_in[13];
  const int*   lengths= (const int*)d_in[14];

  int N = in_sizes[0] / K512;            // 65408

  float* outFinal = (float*)d_out;       // [B,2]
  float* passedZ  = (float*)d_out + 512; // [N,512] fp32

  // workspace carve-up (~342 MB), all offsets 16B-aligned
  char* w = (char*)d_ws;
  int*      offsets = (int*)(w + 0);
  float*    bsum    = (float*)(w + 4096);
  float*    cst     = (float*)(w + 16384);       // 512 KB  (zeroed)
  ushort_t* hA      = (ushort_t*)(w + 540672);   // 256 KB  (zeroed)
  ushort_t* hB      = (ushort_t*)(w + 802816);   // 256 KB  (zeroed)
  float*    seg     = (float*)(w + 1064960);     // 512 KB
  float*    att     = (float*)(w + 1589248);     // 256 KB
  ushort_t* WihB    = (ushort_t*)(w + 1851392);  // 2 MB
  ushort_t* WhhB    = (ushort_t*)(w + 3948544);  // 2 MB
  ushort_t* fc1WB   = (ushort_t*)(w + 6045696);  // 512 KB
  ushort_t* flat    = (ushort_t*)(w + 6569984);  // 67 MB  [N,512] bf16
  ushort_t* xW      = (ushort_t*)(w + 73547776); // 268 MB [N,2048] bf16
  (void)ws_size; (void)n_in; (void)out_size;

  setup_k<<<64, 256, 0, stream>>>(lengths, b_ih, b_hh, offsets, bsum, (uint4*)cst);
  conv_k<<<(G4 * K512 / 8 + 255) / 256, 256, 0, stream>>>(W_ih, WihB, G4 * K512 / 8);
  conv_k<<<(G4 * K512 / 8 + 255) / 256, 256, 0, stream>>>(W_hh, WhhB, G4 * K512 / 8);
  conv_k<<<(K512 * K512 / 8 + 255) / 256, 256, 0, stream>>>(fc1_W, fc1WB, K512 * K512 / 8);

  // xW = lstm_input @ W_ih^T + (b_ih + b_hh)  [N,2048] bf16
  dim3 gx(G4 / 128, (N + 127) / 128);
  mfma_gemm_nt<true, true><<<gx, 256, 0, stream>>>(lstm_input, WihB, bsum, xW, N, G4);

  // sequential recurrence
  dim3 gs(K512 / 16, NPERS / 64);        // 32 x 4 = 128 blocks
  for (int t = 0; t < T_MAX; ++t){
    const ushort_t* hi = (t & 1) ? hB : hA;
    ushort_t*       ho = (t & 1) ? hA : hB;
    step_k<<<gs, 256, 0, stream>>>(hi, ho, cst, xW, WhhB, flat, offsets, lengths, t);
  }

  // passed_Z = flat @ fc1_W^T + fc1_b  -> d_out (fp32)
  dim3 gf(K512 / 128, (N + 127) / 128);
  mfma_gemm_nt<false, false><<<gf, 256, 0, stream>>>(flat, fc1WB, fc1_b, passedZ, N, K512);

  att_k<<<(N + 3) / 4, 256, 0, stream>>>(passedZ, eps_u, fc2_W, fc2_b, att, N);
  seg_k<<<NPERS, 256, 0, stream>>>(flat, att, offsets, lengths, seg);
  final_k<<<NPERS, 64, 0, stream>>>(seg, m1W, m1b, m2W, m2b, outFinal);
}